// Round 13
// baseline (26975.327 us; speedup 1.0000x reference)
//
#include <hip/hip_runtime.h>
#include <math.h>

// NCA: B=8, H=W=256, C=16, 16 steps. fp32.
// R12 post-mortem: limiter = LDS instruction pipe (~1150 instrs/wave: 512
// broadcast w0s reads + 544 shfl/ds_swizzle); conflict counter tracks instr
// count, invariant across layouts. VALU not the bottleneck (47% busy, dur flat).
// R13: weights via SCALAR path. Wave owns j-range (readfirstlane wid), lane=px:
// W0/b0/W1 addresses wave-uniform -> s_load (K$), FMA = v_fmac vD, sW, vA.
// No w0s staging, no kq shuffles, 2 barriers instead of 18. perc read = own-row
// b128 (baseline-optimal). j-reduce via dxp LDS (stride 17, b32, 2-way).

#define HW 256
#define NPIX (8*HW*HW)   // 524288

__device__ __forceinline__ float4 f4max(float4 a, float4 b) {
    return make_float4(fmaxf(a.x,b.x), fmaxf(a.y,b.y), fmaxf(a.z,b.z), fmaxf(a.w,b.w));
}

// Precompute sobel bank (6 filters, 7x7, normalized).
__global__ void init_kernel(const float* __restrict__ W0,
                            float* __restrict__ filt) {
    int t = blockIdx.x * blockDim.x + threadIdx.x;
    if (t < 6) {
        int f = t;
        int size = 3 + 2*(f >> 1);
        int p0 = (7 - size) >> 1;
        int isY = f & 1;
        float vals[49];
        float norm = 0.f;
        for (int a = 0; a < 7; a++) {
            for (int b = 0; b < 7; b++) {
                float v = 0.f;
                if (a >= p0 && a < p0+size && b >= p0 && b < p0+size) {
                    float fy = (float)(a - 3), fx = (float)(b - 3);
                    float den = fx*fx + fy*fy;
                    if (den == 0.f) den = 1.f;
                    v = (isY ? fy : fx) / den;
                }
                vals[a*7+b] = v;
                norm += fabsf(v);
            }
        }
        float inv = 1.f / norm;
        for (int i = 0; i < 49; i++) filt[f*49 + i] = vals[i] * inv;
    }
}

// One 8x8 pixel tile per block, 256 threads.
// Phase 1: thread=(pixel p=t&63, chan-quad q=t>>6): conv/pools -> perc LDS.
// Phase 2: wave wid owns j [64wid,64wid+64) (2 passes of 32); lane = px.
__launch_bounds__(256, 3)
__global__ void step_main(const float* __restrict__ x,
                          float* __restrict__ xmid,
                          float* __restrict__ alpha_out,
                          float* __restrict__ prelife_out,
                          const float* __restrict__ filt_g,
                          const float* __restrict__ W0,
                          const float* __restrict__ b0,
                          const float* __restrict__ W1,
                          const float* __restrict__ stoch_s) {
    // carve: [0,4352): xs 3920 + filt 294 (phase1) / dxp 4x64x17 (phase2 tail)
    //        [4352,12800): perc 64x132
    // total 51200 B -> 3 blocks/CU (153.6 KB)
    __shared__ float smem[12800];
    float* xs     = smem;            // 14*14*20 = 3920 (phase 1 only)
    float* filt_s = smem + 3920;     // 294 (phase 1 only)
    float* dxp    = smem;            // [4][64][17] = 4352 (phase 2 tail)
    float* perc   = smem + 4352;     // 64 x 132 = 8448

    const int t   = threadIdx.x;
    const int b   = blockIdx.z;
    const int ty0 = blockIdx.y * 8;
    const int tx0 = blockIdx.x * 8;

    for (int i = t; i < 294; i += 256) filt_s[i] = filt_g[i];

    // stage x tile + halo (zero pad = conv's zero padding)
    for (int v = t; v < 784; v += 256) {          // 14*14*4 float4s
        int c4  = v & 3;
        int cell = v >> 2;
        int ly = cell / 14;
        int lx = cell - ly*14;
        int gy = ty0 + ly - 3, gx = tx0 + lx - 3;
        float4 val = make_float4(0.f,0.f,0.f,0.f);
        if ((unsigned)gy < 256u && (unsigned)gx < 256u)
            val = *(const float4*)&x[((((b<<8) + gy)<<8) + gx)*16 + (c4<<2)];
        *(float4*)&xs[cell*20 + (c4<<2)] = val;
    }
    __syncthreads();

    {   // ---- phase 1: conv + pools -> perc ----
        const int p  = t & 63;
        const int q  = t >> 6;
        const int py = p >> 3, px1 = p & 7;
        const int gy = ty0 + py, gx = tx0 + px1;
        const int q4 = q << 2;

        float4 y4[6];
        #pragma unroll
        for (int f = 0; f < 6; f++) y4[f] = make_float4(0.f,0.f,0.f,0.f);

        #pragma unroll
        for (int a = 0; a < 7; a++) {
            #pragma unroll
            for (int bb = 0; bb < 7; bb++) {
                float4 xv = *(const float4*)&xs[((py+a)*14 + (px1+bb))*20 + q4];
                #pragma unroll
                for (int f = 0; f < 6; f++) {
                    float w = filt_s[f*49 + a*7 + bb];
                    y4[f].x = fmaf(w, xv.x, y4[f].x);
                    y4[f].y = fmaf(w, xv.y, y4[f].y);
                    y4[f].z = fmaf(w, xv.z, y4[f].z);
                    y4[f].w = fmaf(w, xv.w, y4[f].w);
                }
            }
        }
        float4 m5 = make_float4(-INFINITY,-INFINITY,-INFINITY,-INFINITY);
        #pragma unroll
        for (int dy = -2; dy <= 2; dy++) {
            #pragma unroll
            for (int dx2 = -2; dx2 <= 2; dx2++) {
                if ((unsigned)(gy+dy) < 256u && (unsigned)(gx+dx2) < 256u)
                    m5 = f4max(m5, *(const float4*)&xs[((py+3+dy)*14 + (px1+3+dx2))*20 + q4]);
            }
        }
        // perc: plain layout [0:16)=x, [16+f*16+c)=y (f-major), [112:128)=pool5
        float4 xc = *(const float4*)&xs[((py+3)*14 + (px1+3))*20 + q4];
        *(float4*)&perc[p*132 + q4] = xc;
        #pragma unroll
        for (int f = 0; f < 6; f++)
            *(float4*)&perc[p*132 + 16 + f*16 + q4] = y4[f];
        *(float4*)&perc[p*132 + 112 + q4] = m5;

        if (q == 0) {
            float pre = -INFINITY;
            #pragma unroll
            for (int dy = -1; dy <= 1; dy++) {
                #pragma unroll
                for (int dx2 = -1; dx2 <= 1; dx2++) {
                    if ((unsigned)(gy+dy) < 256u && (unsigned)(gx+dx2) < 256u)
                        pre = fmaxf(pre, xs[((py+3+dy)*14 + (px1+3+dx2))*20 + 3]);
                }
            }
            prelife_out[(b << 16) + (gy << 8) + gx] = (pre > 0.1f) ? 1.f : 0.f;
        }
    }
    __syncthreads();   // perc visible; xs/filt dead (dxp region free)

    // ---- phase 2: MLP. wave wid owns j [64wid,64wid+64); lane = px ----
    const int wid = __builtin_amdgcn_readfirstlane(t >> 6);   // provably uniform
    const int px  = t & 63;
    const float* percP = &perc[px * 132];

    float dx[16];
    #pragma unroll
    for (int c = 0; c < 16; c++) dx[c] = 0.f;

    #pragma unroll 1
    for (int pass = 0; pass < 2; pass++) {
        const int jbase = (wid << 6) + (pass << 5);   // uniform
        float h[32];
        #pragma unroll
        for (int jj = 0; jj < 32; jj++) h[jj] = 0.f;

        #pragma unroll 2
        for (int k4 = 0; k4 < 128; k4 += 4) {
            float4 av = *(const float4*)&percP[k4];   // own-row b128
            #pragma unroll
            for (int kk = 0; kk < 4; kk++) {
                float a = kk==0?av.x : kk==1?av.y : kk==2?av.z : av.w;
                const float4* wr = (const float4*)(W0 + (k4 + kk)*256 + jbase); // uniform -> s_load
                float4 w0v = wr[0], w1v = wr[1], w2v = wr[2], w3v = wr[3];
                float4 w4v = wr[4], w5v = wr[5], w6v = wr[6], w7v = wr[7];
                h[0]  = fmaf(a, w0v.x, h[0]);  h[1]  = fmaf(a, w0v.y, h[1]);
                h[2]  = fmaf(a, w0v.z, h[2]);  h[3]  = fmaf(a, w0v.w, h[3]);
                h[4]  = fmaf(a, w1v.x, h[4]);  h[5]  = fmaf(a, w1v.y, h[5]);
                h[6]  = fmaf(a, w1v.z, h[6]);  h[7]  = fmaf(a, w1v.w, h[7]);
                h[8]  = fmaf(a, w2v.x, h[8]);  h[9]  = fmaf(a, w2v.y, h[9]);
                h[10] = fmaf(a, w2v.z, h[10]); h[11] = fmaf(a, w2v.w, h[11]);
                h[12] = fmaf(a, w3v.x, h[12]); h[13] = fmaf(a, w3v.y, h[13]);
                h[14] = fmaf(a, w3v.z, h[14]); h[15] = fmaf(a, w3v.w, h[15]);
                h[16] = fmaf(a, w4v.x, h[16]); h[17] = fmaf(a, w4v.y, h[17]);
                h[18] = fmaf(a, w4v.z, h[18]); h[19] = fmaf(a, w4v.w, h[19]);
                h[20] = fmaf(a, w5v.x, h[20]); h[21] = fmaf(a, w5v.y, h[21]);
                h[22] = fmaf(a, w5v.z, h[22]); h[23] = fmaf(a, w5v.w, h[23]);
                h[24] = fmaf(a, w6v.x, h[24]); h[25] = fmaf(a, w6v.y, h[25]);
                h[26] = fmaf(a, w6v.z, h[26]); h[27] = fmaf(a, w6v.w, h[27]);
                h[28] = fmaf(a, w7v.x, h[28]); h[29] = fmaf(a, w7v.y, h[29]);
                h[30] = fmaf(a, w7v.z, h[30]); h[31] = fmaf(a, w7v.w, h[31]);
            }
        }
        // bias + relu (uniform b0)
        {
            const float4* bv = (const float4*)(b0 + jbase);
            float4 b0v = bv[0], b1v = bv[1], b2v = bv[2], b3v = bv[3];
            float4 b4v = bv[4], b5v = bv[5], b6v = bv[6], b7v = bv[7];
            h[0]  = fmaxf(h[0]  + b0v.x, 0.f); h[1]  = fmaxf(h[1]  + b0v.y, 0.f);
            h[2]  = fmaxf(h[2]  + b0v.z, 0.f); h[3]  = fmaxf(h[3]  + b0v.w, 0.f);
            h[4]  = fmaxf(h[4]  + b1v.x, 0.f); h[5]  = fmaxf(h[5]  + b1v.y, 0.f);
            h[6]  = fmaxf(h[6]  + b1v.z, 0.f); h[7]  = fmaxf(h[7]  + b1v.w, 0.f);
            h[8]  = fmaxf(h[8]  + b2v.x, 0.f); h[9]  = fmaxf(h[9]  + b2v.y, 0.f);
            h[10] = fmaxf(h[10] + b2v.z, 0.f); h[11] = fmaxf(h[11] + b2v.w, 0.f);
            h[12] = fmaxf(h[12] + b3v.x, 0.f); h[13] = fmaxf(h[13] + b3v.y, 0.f);
            h[14] = fmaxf(h[14] + b3v.z, 0.f); h[15] = fmaxf(h[15] + b3v.w, 0.f);
            h[16] = fmaxf(h[16] + b4v.x, 0.f); h[17] = fmaxf(h[17] + b4v.y, 0.f);
            h[18] = fmaxf(h[18] + b4v.z, 0.f); h[19] = fmaxf(h[19] + b4v.w, 0.f);
            h[20] = fmaxf(h[20] + b5v.x, 0.f); h[21] = fmaxf(h[21] + b5v.y, 0.f);
            h[22] = fmaxf(h[22] + b5v.z, 0.f); h[23] = fmaxf(h[23] + b5v.w, 0.f);
            h[24] = fmaxf(h[24] + b6v.x, 0.f); h[25] = fmaxf(h[25] + b6v.y, 0.f);
            h[26] = fmaxf(h[26] + b6v.z, 0.f); h[27] = fmaxf(h[27] + b6v.w, 0.f);
            h[28] = fmaxf(h[28] + b7v.x, 0.f); h[29] = fmaxf(h[29] + b7v.y, 0.f);
            h[30] = fmaxf(h[30] + b7v.z, 0.f); h[31] = fmaxf(h[31] + b7v.w, 0.f);
        }
        // GEMM2: dx += h[jj] * W1[jbase+jj][0..16)  (uniform W1)
        #pragma unroll
        for (int jj = 0; jj < 32; jj++) {
            const float4* w1r = (const float4*)(W1 + ((jbase + jj) << 4));
            float4 wa = w1r[0], wb = w1r[1], wc = w1r[2], wd = w1r[3];
            float hv = h[jj];
            dx[0]  = fmaf(hv, wa.x, dx[0]);  dx[1]  = fmaf(hv, wa.y, dx[1]);
            dx[2]  = fmaf(hv, wa.z, dx[2]);  dx[3]  = fmaf(hv, wa.w, dx[3]);
            dx[4]  = fmaf(hv, wb.x, dx[4]);  dx[5]  = fmaf(hv, wb.y, dx[5]);
            dx[6]  = fmaf(hv, wb.z, dx[6]);  dx[7]  = fmaf(hv, wb.w, dx[7]);
            dx[8]  = fmaf(hv, wc.x, dx[8]);  dx[9]  = fmaf(hv, wc.y, dx[9]);
            dx[10] = fmaf(hv, wc.z, dx[10]); dx[11] = fmaf(hv, wc.w, dx[11]);
            dx[12] = fmaf(hv, wd.x, dx[12]); dx[13] = fmaf(hv, wd.y, dx[13]);
            dx[14] = fmaf(hv, wd.z, dx[14]); dx[15] = fmaf(hv, wd.w, dx[15]);
        }
    }

    // park this wave's partial dx: dxp[wid][px][17]
    {
        float* dpw = &dxp[(wid << 6) * 17 + px * 17];
        dpw[0]  = dx[0];  dpw[1]  = dx[1];  dpw[2]  = dx[2];  dpw[3]  = dx[3];
        dpw[4]  = dx[4];  dpw[5]  = dx[5];  dpw[6]  = dx[6];  dpw[7]  = dx[7];
        dpw[8]  = dx[8];  dpw[9]  = dx[9];  dpw[10] = dx[10]; dpw[11] = dx[11];
        dpw[12] = dx[12]; dpw[13] = dx[13]; dpw[14] = dx[14]; dpw[15] = dx[15];
    }
    __syncthreads();

    // epilogue: thread = (pixel ep=t>>2, chan-quad cq=t&3); sum 4 partials
    const int ep = t >> 2;
    const int cq = t & 3;
    const int co = cq << 2;
    float s0 = 0.f, s1 = 0.f, s2 = 0.f, s3 = 0.f;
    #pragma unroll
    for (int w = 0; w < 4; w++) {
        const float* dpr = &dxp[(w << 6) * 17 + ep * 17 + co];
        s0 += dpr[0]; s1 += dpr[1]; s2 += dpr[2]; s3 += dpr[3];
    }
    const int ppy = ep >> 3, ppx = ep & 7;
    const int pix2 = (b << 16) + ((ty0 + ppy) << 8) + (tx0 + ppx);
    float fire = (stoch_s[pix2] > 0.5f) ? 1.f : 0.f;
    float4 xc2 = *(const float4*)&perc[ep*132 + co];
    float4 xn;
    xn.x = fmaf(fire, s0, xc2.x);
    xn.y = fmaf(fire, s1, xc2.y);
    xn.z = fmaf(fire, s2, xc2.z);
    xn.w = fmaf(fire, s3, xc2.w);
    *(float4*)&xmid[((size_t)pix2 << 4) + co] = xn;
    if (cq == 0) { /* nothing */ }
    if (cq == 0) ;   // alpha is channel 3 = cq0's .w
    if (cq == 0) alpha_out[pix2] = xn.w;
}

// In-place life masking: reads alpha_new from the separate plane (race-free).
__global__ void step_mask(float* __restrict__ xbuf,
                          const float* __restrict__ alpha,
                          const float* __restrict__ prelife,
                          const float* __restrict__ valid) {
    int pix = blockIdx.x * 256 + threadIdx.x;
    int b = pix >> 16;
    int y = (pix >> 8) & 255;
    int x = pix & 255;
    float m = -INFINITY;
    #pragma unroll
    for (int dy = -1; dy <= 1; dy++) {
        #pragma unroll
        for (int dxo = -1; dxo <= 1; dxo++) {
            int yy = y + dy, xx = x + dxo;
            if ((unsigned)yy < 256u && (unsigned)xx < 256u)
                m = fmaxf(m, alpha[(b << 16) + (yy << 8) + xx]);
        }
    }
    float life = (prelife[pix] != 0.f && m > 0.1f) ? 1.f : 0.f;
    float s = life * valid[pix];
    float4* xp = (float4*)&xbuf[(size_t)pix << 4];
    #pragma unroll
    for (int i = 0; i < 4; i++) {
        float4 v = xp[i];
        v.x *= s; v.y *= s; v.z *= s; v.w *= s;
        xp[i] = v;
    }
}

extern "C" void kernel_launch(void* const* d_in, const int* in_sizes, int n_in,
                              void* d_out, int out_size, void* d_ws, size_t ws_size,
                              hipStream_t stream) {
    const float* x0    = (const float*)d_in[0];
    const float* valid = (const float*)d_in[1];
    const float* stoch = (const float*)d_in[2];
    const float* W0    = (const float*)d_in[3];
    const float* b0    = (const float*)d_in[4];
    const float* W1    = (const float*)d_in[5];

    float* ws      = (float*)d_ws;
    float* xA      = ws;                 // 8388608 floats
    float* alpha   = ws + 8388608;       // 524288
    float* prelife = ws + 8912896;       // 524288
    float* filt    = ws + 9437184;       // 294 (+pad)
    float* out     = (float*)d_out;

    init_kernel<<<1, 64, 0, stream>>>(W0, filt);

    const float* src = x0;
    for (int k = 1; k <= 16; k++) {
        float* dst = (k & 1) ? xA : out;   // step 16 (even) lands in d_out
        step_main<<<dim3(32,32,8), 256, 0, stream>>>(
            src, dst, alpha, prelife, filt, W0, b0, W1,
            stoch + (size_t)(k-1)*NPIX);
        step_mask<<<NPIX/256, 256, 0, stream>>>(dst, alpha, prelife, valid);
        src = dst;
    }
}